// Round 11
// baseline (397.400 us; speedup 1.0000x reference)
//
#include <hip/hip_runtime.h>

#define SEQ 4096
#define DM  768
#define NH  12
#define DK  64

typedef __bf16 bf16_t;
typedef bf16_t bf16x8 __attribute__((ext_vector_type(8)));
typedef bf16_t bf16x4 __attribute__((ext_vector_type(4)));
typedef float  f32x4  __attribute__((ext_vector_type(4)));
typedef short  s16x4  __attribute__((ext_vector_type(4)));

#define LOG2E 1.44269504088896340736f
#define SM_C  16.0f   // fixed softmax shift; scale cancels in O/l

static __device__ inline f32x4 mfma16x16x16_bf16(bf16x4 a, bf16x4 b, f32x4 c) {
#if __has_builtin(__builtin_amdgcn_mfma_f32_16x16x16_bf16)
    return __builtin_amdgcn_mfma_f32_16x16x16_bf16(a, b, c, 0, 0, 0);
#else
    return __builtin_amdgcn_mfma_f32_16x16x16bf16_1k(
        __builtin_bit_cast(s16x4, a), __builtin_bit_cast(s16x4, b), c, 0, 0, 0);
#endif
}

// async global->LDS, 16 B per lane; LDS dest = wave-uniform base + lane*16
static __device__ __forceinline__ void gl_lds16(const bf16_t* g, bf16_t* l) {
    __builtin_amdgcn_global_load_lds(
        (const __attribute__((address_space(1))) void*)g,
        (__attribute__((address_space(3))) void*)l, 16, 0, 0);
}

// ---------------------------------------------------------------------------
// fp32 -> bf16 bulk convert (x, Wq..Wo)  +  zero Oacc/Lacc (merged memset)
// ---------------------------------------------------------------------------
__global__ __launch_bounds__(256) void cvt_zero(
    const float* __restrict__ x,  const float* __restrict__ Wq,
    const float* __restrict__ Wk, const float* __restrict__ Wv,
    const float* __restrict__ Wo,
    bf16_t* __restrict__ xb, bf16_t* __restrict__ Wb,
    float* __restrict__ zf)
{
    const int NXV  = SEQ * DM / 4;
    const int NWV  = DM * DM / 4;
    const int NCVT = NXV + 4 * NWV;
    int i4 = blockIdx.x * 256 + threadIdx.x;
    if (i4 < NCVT) {
        const float* src; bf16_t* dst; int off;
        if (i4 < NXV) { src = x; dst = xb; off = i4; }
        else {
            int j = i4 - NXV;
            int w = j / NWV, jj = j - w * NWV;
            src = (w == 0) ? Wq : (w == 1) ? Wk : (w == 2) ? Wv : Wo;
            dst = Wb + (size_t)w * DM * DM;
            off = jj;
        }
        float4 v = *(const float4*)&src[(size_t)off * 4];
        bf16x4 t;
        t[0] = (bf16_t)v.x; t[1] = (bf16_t)v.y;
        t[2] = (bf16_t)v.z; t[3] = (bf16_t)v.w;
        *(bf16x4*)&dst[(size_t)off * 4] = t;
    } else {
        int j = i4 - NCVT;
        *(float4*)&zf[(size_t)j * 4] = (float4){0.f, 0.f, 0.f, 0.f};
    }
}

// ---------------------------------------------------------------------------
// m97-style GEMM (BK=64, global_load_lds 16B, XOR-chunk swizzle) — round-6.
// z = {Q,K,V}; K pre-scaled by 1/8; V stored transposed [DM][SEQ].
// ---------------------------------------------------------------------------
__global__ __launch_bounds__(256) void gemm_qkv2(
    const bf16_t* __restrict__ A, const bf16_t* __restrict__ Wb,
    const float* __restrict__ bq, const float* __restrict__ bk,
    const float* __restrict__ bv,
    bf16_t* __restrict__ Qb, bf16_t* __restrict__ Kb, bf16_t* __restrict__ Vbt)
{
    const int z = blockIdx.z;
    const bf16_t* W = Wb + (size_t)z * DM * DM;
    const float* bias = (z == 0) ? bq : (z == 1) ? bk : bv;

    __shared__ bf16_t As[128][64];
    __shared__ bf16_t Bs[128][64];

    const int tid  = threadIdx.x;
    const int wave = tid >> 6;
    const int lane = tid & 63;
    const int wm   = wave & 1, wn = wave >> 1;
    const int lrow = lane & 15;
    const int quad = lane >> 4;
    const int row0 = blockIdx.x * 128;
    const int col0 = blockIdx.y * 128;

    const int srow   = lane >> 3;
    const int schunk = (lane & 7) ^ srow;
    const int swz    = lrow & 7;

    f32x4 acc[4][4];
    #pragma unroll
    for (int i = 0; i < 4; i++)
        #pragma unroll
        for (int j = 0; j < 4; j++)
            acc[i][j] = (f32x4){0.f, 0.f, 0.f, 0.f};

    for (int k0 = 0; k0 < DM; k0 += 64) {
        __syncthreads();
        #pragma unroll
        for (int u = 0; u < 4; u++) {
            int R0 = wave * 32 + u * 8;
            gl_lds16(&A[(size_t)(row0 + R0 + srow) * DM + k0 + schunk * 8],
                     &As[R0][0]);
            gl_lds16(&W[(size_t)(col0 + R0 + srow) * DM + k0 + schunk * 8],
                     &Bs[R0][0]);
        }
        __syncthreads();

        #pragma unroll
        for (int s = 0; s < 2; s++) {
            bf16x8 af[4], bfr[4];
            #pragma unroll
            for (int mt = 0; mt < 4; mt++)
                af[mt] = *(const bf16x8*)
                    &As[wm * 64 + mt * 16 + lrow][(((s << 2) | quad) ^ swz) * 8];
            #pragma unroll
            for (int nt = 0; nt < 4; nt++)
                bfr[nt] = *(const bf16x8*)
                    &Bs[wn * 64 + nt * 16 + lrow][(((s << 2) | quad) ^ swz) * 8];
            #pragma unroll
            for (int mt = 0; mt < 4; mt++)
                #pragma unroll
                for (int nt = 0; nt < 4; nt++)
                    acc[mt][nt] = __builtin_amdgcn_mfma_f32_16x16x32_bf16(
                        af[mt], bfr[nt], acc[mt][nt], 0, 0, 0);
        }
    }

    if (z == 2) {
        #pragma unroll
        for (int nt = 0; nt < 4; nt++) {
            int col = col0 + wn * 64 + nt * 16 + lrow;
            float bvv = bias[col];
            #pragma unroll
            for (int mt = 0; mt < 4; mt++) {
                int row = row0 + wm * 64 + mt * 16 + quad * 4;
                bf16x4 t;
                #pragma unroll
                for (int r = 0; r < 4; r++) t[r] = (bf16_t)(acc[mt][nt][r] + bvv);
                *(bf16x4*)&Vbt[(size_t)col * SEQ + row] = t;
            }
        }
    } else {
        bf16_t* Cout = (z == 0) ? Qb : Kb;
        float scale = (z == 1) ? 0.125f : 1.0f;
        #pragma unroll
        for (int nt = 0; nt < 4; nt++) {
            int col = col0 + wn * 64 + nt * 16 + lrow;
            float bvv = bias[col];
            #pragma unroll
            for (int mt = 0; mt < 4; mt++) {
                #pragma unroll
                for (int r = 0; r < 4; r++) {
                    int row = row0 + wm * 64 + mt * 16 + quad * 4 + r;
                    Cout[(size_t)row * DM + col] =
                        (bf16_t)((acc[mt][nt][r] + bvv) * scale);
                }
            }
        }
    }
}

// ---------------------------------------------------------------------------
// out[M,N](f32) = A[M,K](bf16)*W[N,K]^T(bf16)+bias. Tile 128x64 — round-6.
// ---------------------------------------------------------------------------
__global__ __launch_bounds__(256) void gemm_out2(
    const bf16_t* __restrict__ A, const bf16_t* __restrict__ W,
    const float* __restrict__ bias, float* __restrict__ C)
{
    __shared__ bf16_t As[128][64];
    __shared__ bf16_t Bs[64][64];

    const int tid  = threadIdx.x;
    const int wave = tid >> 6;
    const int lane = tid & 63;
    const int wm   = wave & 1, wn = wave >> 1;
    const int lrow = lane & 15;
    const int quad = lane >> 4;
    const int row0 = blockIdx.x * 128;
    const int col0 = blockIdx.y * 64;

    const int srow   = lane >> 3;
    const int schunk = (lane & 7) ^ srow;
    const int swz    = lrow & 7;

    f32x4 acc[4][2];
    #pragma unroll
    for (int i = 0; i < 4; i++)
        #pragma unroll
        for (int j = 0; j < 2; j++)
            acc[i][j] = (f32x4){0.f, 0.f, 0.f, 0.f};

    for (int k0 = 0; k0 < DM; k0 += 64) {
        __syncthreads();
        #pragma unroll
        for (int u = 0; u < 4; u++) {
            int R0 = wave * 32 + u * 8;
            gl_lds16(&A[(size_t)(row0 + R0 + srow) * DM + k0 + schunk * 8],
                     &As[R0][0]);
        }
        #pragma unroll
        for (int u = 0; u < 2; u++) {
            int R0 = wave * 16 + u * 8;
            gl_lds16(&W[(size_t)(col0 + R0 + srow) * DM + k0 + schunk * 8],
                     &Bs[R0][0]);
        }
        __syncthreads();

        #pragma unroll
        for (int s = 0; s < 2; s++) {
            bf16x8 af[4], bfr[2];
            #pragma unroll
            for (int mt = 0; mt < 4; mt++)
                af[mt] = *(const bf16x8*)
                    &As[wm * 64 + mt * 16 + lrow][(((s << 2) | quad) ^ swz) * 8];
            #pragma unroll
            for (int nt = 0; nt < 2; nt++)
                bfr[nt] = *(const bf16x8*)
                    &Bs[wn * 32 + nt * 16 + lrow][(((s << 2) | quad) ^ swz) * 8];
            #pragma unroll
            for (int mt = 0; mt < 4; mt++)
                #pragma unroll
                for (int nt = 0; nt < 2; nt++)
                    acc[mt][nt] = __builtin_amdgcn_mfma_f32_16x16x32_bf16(
                        af[mt], bfr[nt], acc[mt][nt], 0, 0, 0);
        }
    }

    #pragma unroll
    for (int nt = 0; nt < 2; nt++) {
        int col = col0 + wn * 32 + nt * 16 + lrow;
        float bvv = bias[col];
        #pragma unroll
        for (int mt = 0; mt < 4; mt++) {
            #pragma unroll
            for (int r = 0; r < 4; r++) {
                int row = row0 + wm * 64 + mt * 16 + quad * 4 + r;
                C[(size_t)row * DM + col] = acc[mt][nt][r] + bvv;
            }
        }
    }
}

// ---------------------------------------------------------------------------
// Flash attention, BARRIER-FREE / LDS-FREE. Transposed scores mean every
// MFMA operand is per-lane contiguous in global: K A-frags (16B rows of Kb),
// V A-frags (8B rows of Vbt), P born in registers, O stays in registers.
// Wave = 32 q rows (2 groups, shared K/V loads), 16-key tiles, prefetch.
// Waves fully independent (diverge/retire freely) -> no convoy, no drain.
// Additive partials (fixed-shift softmax) -> fp32 atomics.
// grid (32 x 128-q tiles, 8 x 512-key chunks, 12 heads).
// ---------------------------------------------------------------------------
__global__ __launch_bounds__(256, 4) void flash_nosync(
    const bf16_t* __restrict__ Qb, const bf16_t* __restrict__ Kb,
    const bf16_t* __restrict__ Vbt,
    float* __restrict__ Oacc /* [NH][DK][SEQ] */,
    float* __restrict__ Lacc /* [NH][SEQ] */)
{
    const int qt = blockIdx.x;                    // q rows [128qt, 128qt+127]
    const int kc = blockIdx.y;                    // keys [512kc, 512kc+511]
    if (kc * 512 > qt * 128 + 127) return;        // block-uniform
    const int h    = blockIdx.z;
    const int tid  = threadIdx.x;
    const int wave = tid >> 6;
    const int lane = tid & 63;
    const int lrow = lane & 15;
    const int quad = lane >> 4;

    const int ma = 8 * qt + 2 * wave;             // group-a diagonal 16-tile
    const int mb = ma + 1;                        // group-b diagonal 16-tile
    const int ktbeg = kc * 32;
    const int ktend = min(kc * 32 + 31, mb);
    if (ktbeg > ktend) return;                    // wave-level exit: OK, no barriers

    // Q B-fragments for both groups (q rows ma*16.., mb*16..)
    size_t qra = (size_t)(ma * 16 + lrow) * DM + h * DK;
    size_t qrb = qra + (size_t)16 * DM;
    bf16x8 qa0 = *(const bf16x8*)&Qb[qra + quad * 8];
    bf16x8 qa1 = *(const bf16x8*)&Qb[qra + 32 + quad * 8];
    bf16x8 qb0 = *(const bf16x8*)&Qb[qrb + quad * 8];
    bf16x8 qb1 = *(const bf16x8*)&Qb[qrb + 32 + quad * 8];

    f32x4 oa[4], ob[4];
    #pragma unroll
    for (int dt = 0; dt < 4; dt++) {
        oa[dt] = (f32x4){0.f, 0.f, 0.f, 0.f};
        ob[dt] = (f32x4){0.f, 0.f, 0.f, 0.f};
    }
    float la = 0.f, lb = 0.f;

    const bf16_t* Kp = Kb  + (size_t)h * DK;
    const bf16_t* Vp = Vbt + (size_t)(h * DK) * SEQ;

    // prefetch first tile
    bf16x8 kf0, kf1;
    bf16x4 vf0, vf1, vf2, vf3;
    {
        int kb = ktbeg * 16;
        const bf16_t* kr = Kp + (size_t)(kb + lrow) * DM + quad * 8;
        kf0 = *(const bf16x8*)kr;
        kf1 = *(const bf16x8*)(kr + 32);
        vf0 = *(const bf16x4*)&Vp[(size_t)(lrow)      * SEQ + kb + quad * 4];
        vf1 = *(const bf16x4*)&Vp[(size_t)(16 + lrow) * SEQ + kb + quad * 4];
        vf2 = *(const bf16x4*)&Vp[(size_t)(32 + lrow) * SEQ + kb + quad * 4];
        vf3 = *(const bf16x4*)&Vp[(size_t)(48 + lrow) * SEQ + kb + quad * 4];
    }

    for (int kt = ktbeg; kt <= ktend; kt++) {
        bf16x8 ck0 = kf0, ck1 = kf1;
        bf16x4 cv0 = vf0, cv1 = vf1, cv2 = vf2, cv3 = vf3;
        if (kt < ktend) {                         // prefetch next tile
            int kb = (kt + 1) * 16;
            const bf16_t* kr = Kp + (size_t)(kb + lrow) * DM + quad * 8;
            kf0 = *(const bf16x8*)kr;
            kf1 = *(const bf16x8*)(kr + 32);
            vf0 = *(const bf16x4*)&Vp[(size_t)(lrow)      * SEQ + kb + quad * 4];
            vf1 = *(const bf16x4*)&Vp[(size_t)(16 + lrow) * SEQ + kb + quad * 4];
            vf2 = *(const bf16x4*)&Vp[(size_t)(32 + lrow) * SEQ + kb + quad * 4];
            vf3 = *(const bf16x4*)&Vp[(size_t)(48 + lrow) * SEQ + kb + quad * 4];
        }

        // ---- group b (always active: kt <= ktend <= mb) ----
        {
            f32x4 a = (f32x4){0.f, 0.f, 0.f, 0.f};
            a = __builtin_amdgcn_mfma_f32_16x16x32_bf16(ck0, qb0, a, 0, 0, 0);
            a = __builtin_amdgcn_mfma_f32_16x16x32_bf16(ck1, qb1, a, 0, 0, 0);
            if (kt == mb) {
                #pragma unroll
                for (int r = 0; r < 4; r++)
                    if (quad * 4 + r > lrow) a[r] = -1e30f;
            }
            bf16x4 pf;
            float rsum = 0.f;
            #pragma unroll
            for (int r = 0; r < 4; r++) {
                float p = __builtin_amdgcn_exp2f(
                    __builtin_fmaf(a[r], LOG2E, -SM_C * LOG2E));
                rsum += p;
                pf[r] = (bf16_t)p;
            }
            lb += rsum;
            ob[0] = mfma16x16x16_bf16(cv0, pf, ob[0]);
            ob[1] = mfma16x16x16_bf16(cv1, pf, ob[1]);
            ob[2] = mfma16x16x16_bf16(cv2, pf, ob[2]);
            ob[3] = mfma16x16x16_bf16(cv3, pf, ob[3]);
        }

        // ---- group a (skip tiles beyond its diagonal; wave-uniform) ----
        if (kt <= ma) {
            f32x4 a = (f32x4){0.f, 0.f, 0.f, 0.f};
            a = __builtin_amdgcn_mfma_f32_16x16x32_bf16(ck0, qa0, a, 0, 0, 0);
            a = __builtin_amdgcn_mfma_f32_16x16x32_bf16(ck1, qa1, a, 0, 0, 0);
            if (kt == ma) {
                #pragma unroll
                for (int r = 0; r < 4; r++)
                    if (quad * 4 + r > lrow) a[r] = -1e30f;
            }
            bf16x4 pf;
            float rsum = 0.f;
            #pragma unroll
            for (int r = 0; r < 4; r++) {
                float p = __builtin_amdgcn_exp2f(
                    __builtin_fmaf(a[r], LOG2E, -SM_C * LOG2E));
                rsum += p;
                pf[r] = (bf16_t)p;
            }
            la += rsum;
            oa[0] = mfma16x16x16_bf16(cv0, pf, oa[0]);
            oa[1] = mfma16x16x16_bf16(cv1, pf, oa[1]);
            oa[2] = mfma16x16x16_bf16(cv2, pf, oa[2]);
            oa[3] = mfma16x16x16_bf16(cv3, pf, oa[3]);
        }
    }

    // flush additive partials (group a then b)
    #pragma unroll
    for (int dt = 0; dt < 4; dt++)
        #pragma unroll
        for (int r = 0; r < 4; r++) {
            int d = dt * 16 + quad * 4 + r;
            atomicAdd(&Oacc[((size_t)h * DK + d) * SEQ + ma * 16 + lrow], oa[dt][r]);
            atomicAdd(&Oacc[((size_t)h * DK + d) * SEQ + mb * 16 + lrow], ob[dt][r]);
        }
    la += __shfl_xor(la, 16, 64);
    la += __shfl_xor(la, 32, 64);
    lb += __shfl_xor(lb, 16, 64);
    lb += __shfl_xor(lb, 32, 64);
    if (quad == 0) {
        atomicAdd(&Lacc[(size_t)h * SEQ + ma * 16 + lrow], la);
        atomicAdd(&Lacc[(size_t)h * SEQ + mb * 16 + lrow], lb);
    }
}

// ---------------------------------------------------------------------------
// Ctx[q][h*64+d] = Oacc[h][d][q] / Lacc[h][q]
// ---------------------------------------------------------------------------
__global__ __launch_bounds__(256) void ctx_epilogue(
    const float* __restrict__ Oacc, const float* __restrict__ Lacc,
    bf16_t* __restrict__ Ctx)
{
    const int qt = blockIdx.x;
    const int h  = blockIdx.y;
    const int tid = threadIdx.x;
    __shared__ float T[64][65];

    #pragma unroll
    for (int i = 0; i < 4; i++) {
        int v  = tid + i * 256;
        int d  = v >> 4;
        int qv = v & 15;
        f32x4 o4 = *(const f32x4*)&Oacc[((size_t)h * DK + d) * SEQ + qt * 64 + qv * 4];
        f32x4 l4 = *(const f32x4*)&Lacc[(size_t)h * SEQ + qt * 64 + qv * 4];
        #pragma unroll
        for (int j = 0; j < 4; j++)
            T[qv * 4 + j][d] = o4[j] / l4[j];
    }
    __syncthreads();
    #pragma unroll
    for (int i = 0; i < 2; i++) {
        int v  = tid + i * 256;
        int q  = v >> 3;
        int c8 = v & 7;
        bf16x8 t;
        #pragma unroll
        for (int j = 0; j < 8; j++)
            t[j] = (bf16_t)T[q][c8 * 8 + j];
        *(bf16x8*)&Ctx[(size_t)(qt * 64 + q) * DM + h * DK + c8 * 8] = t;
    }
}

// ---------------------------------------------------------------------------
extern "C" void kernel_launch(void* const* d_in, const int* in_sizes, int n_in,
                              void* d_out, int out_size, void* d_ws, size_t ws_size,
                              hipStream_t stream) {
    const float* x  = (const float*)d_in[0];
    const float* Wq = (const float*)d_in[1];
    const float* bq = (const float*)d_in[2];
    const float* Wk = (const float*)d_in[3];
    const float* bk = (const float*)d_in[4];
    const float* Wv = (const float*)d_in[5];
    const float* bv = (const float*)d_in[6];
    const float* Wo = (const float*)d_in[7];
    const float* bo = (const float*)d_in[8];
    float* out = (float*)d_out;

    const size_t NX = (size_t)SEQ * DM;
    const size_t NW = (size_t)DM * DM;

    bf16_t* xb   = (bf16_t*)d_ws;          // reused as Ctx after flash
    bf16_t* Qb   = xb  + NX;
    bf16_t* Kb   = Qb  + NX;
    bf16_t* Vbt  = Kb  + NX;               // transposed [DM][SEQ]
    bf16_t* Wb   = Vbt + NX;               // Wq,Wk,Wv,Wo bf16
    float*  Oacc = (float*)(Wb + 4 * NW);
    float*  Lacc = Oacc + NX;
    bf16_t* Cx   = xb;

    int total_blocks = (1376256 + 798720) / 256;
    cvt_zero<<<total_blocks, 256, 0, stream>>>(x, Wq, Wk, Wv, Wo, xb, Wb, Oacc);

    dim3 g1(SEQ / 128, DM / 128, 3);
    gemm_qkv2<<<g1, 256, 0, stream>>>(xb, Wb, bq, bk, bv, Qb, Kb, Vbt);

    dim3 g2(SEQ / 128, SEQ / 512, NH);     // 32 x 8 x 12
    flash_nosync<<<g2, 256, 0, stream>>>(Qb, Kb, Vbt, Oacc, Lacc);

    dim3 g3(SEQ / 64, NH);
    ctx_epilogue<<<g3, 256, 0, stream>>>(Oacc, Lacc, Cx);

    dim3 g4(SEQ / 128, DM / 64);
    gemm_out2<<<g4, 256, 0, stream>>>(Cx, Wb + 3 * NW, bo, out);
}